// Round 16
// baseline (365.098 us; speedup 1.0000x reference)
//
#include <hip/hip_runtime.h>
#include <hip/hip_bf16.h>
#include <stdint.h>

#define HW 192
#define NC 128
#define KEPS 1e-5f
#define SLICE_B 49152   /* bytes per image in frag layout */

typedef __attribute__((ext_vector_type(8))) short short8;
typedef __attribute__((ext_vector_type(4))) float f32x4;

__device__ __forceinline__ float max3f(float a, float b, float c) {
  float d;
  asm("v_max3_f32 %0, %1, %2, %3" : "=v"(d) : "v"(a), "v"(b), "v"(c));
  return d;
}

// ---------------------------------------------------------------------------
// Prep: f32 [n][C][HW] -> MFMA-fragment layout:
//   16B chunk (tile 0..11, ks 0..3, lane 0..63) at ((tile*4+ks)*64+lane)*16
//   holding img[c = ks*32 + (lane>>4)*8 + j][s = tile*16 + (lane&15)], j=0..7.
// ---------------------------------------------------------------------------
__global__ __launch_bounds__(256)
void prep_kernel(const float* __restrict__ prob,
                 const float* __restrict__ gal,
                 char* __restrict__ probF,
                 char* __restrict__ galF) {
  __shared__ unsigned short lds[32 * 194];
  const int b = blockIdx.x;
  const int slice = b >> 2;
  const int ks = b & 3;
  const bool isProbe = (slice < 64);
  const float* src = isProbe ? prob + (size_t)slice * NC * HW
                             : gal + (size_t)(slice - 64) * NC * HW;
  char* dstBase = isProbe ? probF + (size_t)slice * SLICE_B
                          : galF + (size_t)(slice - 64) * SLICE_B;
  const float* s0 = src + (size_t)(ks * 32) * HW;
  #pragma unroll
  for (int k = 0; k < 24; ++k) {
    int i = k * 256 + threadIdx.x;
    int cp = i / HW;
    int hw = i - cp * HW;
    lds[cp * 194 + hw] =
        __builtin_bit_cast(unsigned short, __float2bfloat16(s0[i]));
  }
  __syncthreads();
  #pragma unroll
  for (int rep = 0; rep < 3; ++rep) {
    int idx = rep * 256 + threadIdx.x;   // 0..767
    int tile = idx >> 6;
    int lane = idx & 63;
    int q = lane >> 4;
    int s = tile * 16 + (lane & 15);
    short8 pack;
    #pragma unroll
    for (int j = 0; j < 8; ++j)
      pack[j] = (short)lds[(q * 8 + j) * 194 + s];
    *(short8*)(dstBase + (((tile * 4 + ks) * 64 + lane) * 16)) = pack;
  }
}

template <int CTRL>
__device__ __forceinline__ float dpp_max(float x) {
  int xi = __builtin_bit_cast(int, x);
  int yi = __builtin_amdgcn_update_dpp(xi, xi, CTRL, 0xf, 0xf, false);
  return fmaxf(x, __builtin_bit_cast(float, yi));
}
__device__ __forceinline__ float ror16_max(float x) {
  x = dpp_max<0x121>(x);
  x = dpp_max<0x122>(x);
  x = dpp_max<0x124>(x);
  x = dpp_max<0x128>(x);
  return x;
}

// ---------------------------------------------------------------------------
// Pair kernel: barrier-free streaming + explicit software pipeline (R12),
// now at 4 blocks/CU: VGPR fits 128 (measured 116), so launch_bounds(256,4)
// doubles resident waves -> TLP x ILP. 2048 blocks = g*32 + pc (2 probes);
// XCD = bid%8 = pc%8. 4 waves = 4 gallery row-groups of 48 (A persistent).
// Per probe: 12 column-groups; acc ping-pong; B 3-buffer 2-ahead rotation.
// ---------------------------------------------------------------------------
__global__ __launch_bounds__(256, 4)
void pair_kernel(const char* __restrict__ galF,
                 const char* __restrict__ probF,
                 const float* __restrict__ fc_w,
                 float* __restrict__ Wout,
                 float* __restrict__ sPart,
                 float* __restrict__ qPart) {
  __shared__ float cmP[2][4][192];   // [probe][wid][col] col-max partials
  __shared__ float rmF[2][192];      // [probe][row] final row-max
  __shared__ float red[2][4];        // [probe][wid] W partials
  __shared__ float red2[8];

  const int tid = threadIdx.x;
  const int lane = tid & 63;
  const int wid = tid >> 6;          // gallery row group: rows wid*48..+47
  const int q = lane >> 4;
  const int r16 = lane & 15;

  const int g = blockIdx.x >> 5;
  const int pc = blockIdx.x & 31;    // probes 2pc, 2pc+1

  // persistent gallery A-frags (coalesced frag loads)
  const char* gB = galF + (size_t)g * SLICE_B + lane * 16;
  short8 a[3][4];
  #pragma unroll
  for (int m = 0; m < 3; ++m)
    #pragma unroll
    for (int ks = 0; ks < 4; ++ks)
      a[m][ks] = *(const short8*)(gB + (((wid * 3 + m) * 4 + ks) * 1024));

  const float w0 = fc_w[tid];                           // feat j = tid
  const float w1 = (tid < 128) ? fc_w[256 + tid] : 0.f; // feat j = 256+tid

  float s_acc = 0.f, q_acc = 0.f;
  const f32x4 zz = (f32x4){0.f, 0.f, 0.f, 0.f};

  #pragma unroll 1
  for (int pi = 0; pi < 2; ++pi) {
    const char* pB = probF + (size_t)(pc * 2 + pi) * SLICE_B + lane * 16;
    float rm[3][4];
    #pragma unroll
    for (int m = 0; m < 3; ++m)
      #pragma unroll
      for (int j = 0; j < 4; ++j) rm[m][j] = -1e30f;

    short8 b00, b01, b02, b03;   // buffer 0
    short8 b10, b11, b12, b13;   // buffer 1
    short8 b20, b21, b22, b23;   // buffer 2
    f32x4 aA0, aA1, aA2;         // acc even
    f32x4 aB0, aB1, aB2;         // acc odd

#define LOADQ(Q0, Q1, Q2, Q3, GRP) do {                         \
    const char* bb_ = pB + (GRP) * 4096;                        \
    Q0 = *(const short8*)(bb_);                                 \
    Q1 = *(const short8*)(bb_ + 1024);                          \
    Q2 = *(const short8*)(bb_ + 2048);                          \
    Q3 = *(const short8*)(bb_ + 3072);                          \
  } while (0)

#define MFMA_G(A0, A1, A2, Q0, Q1, Q2, Q3) do {                              \
    A0 = __builtin_amdgcn_mfma_f32_16x16x32_bf16(a[0][0], Q0, zz, 0, 0, 0);  \
    A1 = __builtin_amdgcn_mfma_f32_16x16x32_bf16(a[1][0], Q0, zz, 0, 0, 0);  \
    A2 = __builtin_amdgcn_mfma_f32_16x16x32_bf16(a[2][0], Q0, zz, 0, 0, 0);  \
    A0 = __builtin_amdgcn_mfma_f32_16x16x32_bf16(a[0][1], Q1, A0, 0, 0, 0);  \
    A1 = __builtin_amdgcn_mfma_f32_16x16x32_bf16(a[1][1], Q1, A1, 0, 0, 0);  \
    A2 = __builtin_amdgcn_mfma_f32_16x16x32_bf16(a[2][1], Q1, A2, 0, 0, 0);  \
    A0 = __builtin_amdgcn_mfma_f32_16x16x32_bf16(a[0][2], Q2, A0, 0, 0, 0);  \
    A1 = __builtin_amdgcn_mfma_f32_16x16x32_bf16(a[1][2], Q2, A1, 0, 0, 0);  \
    A2 = __builtin_amdgcn_mfma_f32_16x16x32_bf16(a[2][2], Q2, A2, 0, 0, 0);  \
    A0 = __builtin_amdgcn_mfma_f32_16x16x32_bf16(a[0][3], Q3, A0, 0, 0, 0);  \
    A1 = __builtin_amdgcn_mfma_f32_16x16x32_bf16(a[1][3], Q3, A1, 0, 0, 0);  \
    A2 = __builtin_amdgcn_mfma_f32_16x16x32_bf16(a[2][3], Q3, A2, 0, 0, 0);  \
  } while (0)

#define REDUCE_G(A0, A1, A2, GRP) do {                                       \
    float m0_ = max3f(A0[0], A0[1], A0[2]);                                  \
    float m1_ = max3f(A0[3], A1[0], A1[1]);                                  \
    float m2_ = max3f(A1[2], A1[3], A2[0]);                                  \
    float m3_ = max3f(A2[1], A2[2], A2[3]);                                  \
    float cm_ = fmaxf(max3f(m0_, m1_, m2_), m3_);                            \
    cm_ = fmaxf(cm_, __shfl_xor(cm_, 16));                                   \
    cm_ = fmaxf(cm_, __shfl_xor(cm_, 32));                                   \
    if (lane < 16) cmP[pi][wid][(GRP) * 16 + r16] = cm_;                     \
    rm[0][0] = fmaxf(rm[0][0], A0[0]); rm[0][1] = fmaxf(rm[0][1], A0[1]);    \
    rm[0][2] = fmaxf(rm[0][2], A0[2]); rm[0][3] = fmaxf(rm[0][3], A0[3]);    \
    rm[1][0] = fmaxf(rm[1][0], A1[0]); rm[1][1] = fmaxf(rm[1][1], A1[1]);    \
    rm[1][2] = fmaxf(rm[1][2], A1[2]); rm[1][3] = fmaxf(rm[1][3], A1[3]);    \
    rm[2][0] = fmaxf(rm[2][0], A2[0]); rm[2][1] = fmaxf(rm[2][1], A2[1]);    \
    rm[2][2] = fmaxf(rm[2][2], A2[2]); rm[2][3] = fmaxf(rm[2][3], A2[3]);    \
  } while (0)

    // prologue: 2 groups in flight
    LOADQ(b00, b01, b02, b03, 0);
    LOADQ(b10, b11, b12, b13, 1);

    __builtin_amdgcn_s_setprio(1);
    // g0
    LOADQ(b20, b21, b22, b23, 2);
    MFMA_G(aA0, aA1, aA2, b00, b01, b02, b03);
    // g1
    LOADQ(b00, b01, b02, b03, 3);
    MFMA_G(aB0, aB1, aB2, b10, b11, b12, b13);
    REDUCE_G(aA0, aA1, aA2, 0);
    // g2
    LOADQ(b10, b11, b12, b13, 4);
    MFMA_G(aA0, aA1, aA2, b20, b21, b22, b23);
    REDUCE_G(aB0, aB1, aB2, 1);
    // g3
    LOADQ(b20, b21, b22, b23, 5);
    MFMA_G(aB0, aB1, aB2, b00, b01, b02, b03);
    REDUCE_G(aA0, aA1, aA2, 2);
    // g4
    LOADQ(b00, b01, b02, b03, 6);
    MFMA_G(aA0, aA1, aA2, b10, b11, b12, b13);
    REDUCE_G(aB0, aB1, aB2, 3);
    // g5
    LOADQ(b10, b11, b12, b13, 7);
    MFMA_G(aB0, aB1, aB2, b20, b21, b22, b23);
    REDUCE_G(aA0, aA1, aA2, 4);
    // g6
    LOADQ(b20, b21, b22, b23, 8);
    MFMA_G(aA0, aA1, aA2, b00, b01, b02, b03);
    REDUCE_G(aB0, aB1, aB2, 5);
    // g7
    LOADQ(b00, b01, b02, b03, 9);
    MFMA_G(aB0, aB1, aB2, b10, b11, b12, b13);
    REDUCE_G(aA0, aA1, aA2, 6);
    // g8
    LOADQ(b10, b11, b12, b13, 10);
    MFMA_G(aA0, aA1, aA2, b20, b21, b22, b23);
    REDUCE_G(aB0, aB1, aB2, 7);
    // g9
    LOADQ(b20, b21, b22, b23, 11);
    MFMA_G(aB0, aB1, aB2, b00, b01, b02, b03);
    REDUCE_G(aA0, aA1, aA2, 8);
    // g10
    MFMA_G(aA0, aA1, aA2, b10, b11, b12, b13);
    REDUCE_G(aB0, aB1, aB2, 9);
    // g11
    MFMA_G(aB0, aB1, aB2, b20, b21, b22, b23);
    REDUCE_G(aA0, aA1, aA2, 10);
    // epilogue
    REDUCE_G(aB0, aB1, aB2, 11);
    __builtin_amdgcn_s_setprio(0);

#undef LOADQ
#undef MFMA_G
#undef REDUCE_G

    // finish row-max: 16-lane DPP fold, publish rows wid*48 + m*16 + q*4 + j
    #pragma unroll
    for (int m = 0; m < 3; ++m)
      #pragma unroll
      for (int j = 0; j < 4; ++j) {
        float v = ror16_max(rm[m][j]);
        if (r16 == j) rmF[pi][wid * 48 + m * 16 + q * 4 + j] = v;
      }
  }

  __syncthreads();   // all partials visible

  // ---- combine: both probes ----
  #pragma unroll
  for (int pi = 0; pi < 2; ++pi) {
    float v;
    if (tid < 192) {
      float c01 = fmaxf(cmP[pi][0][tid], cmP[pi][1][tid]);
      v = max3f(c01, cmP[pi][2][tid], cmP[pi][3][tid]);
    } else {
      v = rmF[pi][tid - 192];          // rows 0..63 -> feat j = tid
    }
    s_acc += v; q_acc += v * v;
    float w = v * w0;
    if (tid < 128) {
      float v1 = rmF[pi][tid + 64];    // rows 64..191 -> feat j = 256+tid
      s_acc += v1; q_acc += v1 * v1;
      w += v1 * w1;
    }
    #pragma unroll
    for (int msk = 1; msk < 64; msk <<= 1) w += __shfl_xor(w, msk);
    if (lane == 0) red[pi][wid] = w;
  }
  #pragma unroll
  for (int msk = 1; msk < 64; msk <<= 1) {
    s_acc += __shfl_xor(s_acc, msk);
    q_acc += __shfl_xor(q_acc, msk);
  }
  if (lane == 0) { red2[wid] = s_acc; red2[4 + wid] = q_acc; }
  __syncthreads();
  if (tid < 2)
    Wout[(pc * 2 + tid) * 64 + g] =
        red[tid][0] + red[tid][1] + red[tid][2] + red[tid][3];
  if (tid == 0) {
    sPart[blockIdx.x] = red2[0] + red2[1] + red2[2] + red2[3];
    qPart[blockIdx.x] = red2[4] + red2[5] + red2[6] + red2[7];
  }
}

// ---------------------------------------------------------------------------
// Finalize: exact BN -> fc -> BN chain. One block, 1024 threads.
// sPart/qPart have 2048 entries.
// ---------------------------------------------------------------------------
__device__ __forceinline__ float block_sum(float v, float* rbuf, float* bc, int nw) {
  int t = threadIdx.x, lane = t & 63, wid = t >> 6;
  #pragma unroll
  for (int m = 1; m < 64; m <<= 1) v += __shfl_xor(v, m);
  if (lane == 0) rbuf[wid] = v;
  __syncthreads();
  if (t == 0) {
    float r = 0.f;
    for (int i = 0; i < nw; ++i) r += rbuf[i];
    bc[0] = r;
  }
  __syncthreads();
  float res = bc[0];
  __syncthreads();
  return res;
}

__global__ __launch_bounds__(1024)
void finalize_kernel(const float* __restrict__ Wv,
                     const float* __restrict__ sPart,
                     const float* __restrict__ qPart,
                     const float* __restrict__ fc_w,
                     const float* __restrict__ fc_b,
                     const float* __restrict__ bn_g,
                     const float* __restrict__ bn_b,
                     const float* __restrict__ lbn_g,
                     const float* __restrict__ lbn_b,
                     float* __restrict__ out) {
  __shared__ float rbuf[16];
  __shared__ float bc[1];
  const int t = threadIdx.x;

  float S = block_sum(sPart[t] + sPart[t + 1024], rbuf, bc, 16);
  float Q = block_sum(qPart[t] + qPart[t + 1024], rbuf, bc, 16);
  float SW = block_sum((t < 384) ? fc_w[t] : 0.f, rbuf, bc, 16);

  const float Nf = 4096.0f * 384.0f;
  float mu = S / Nf;
  float var = Q / Nf - mu * mu;
  float istd = rsqrtf(var + KEPS);
  float cA = istd * bn_g[0];
  float off = bn_b[0] * SW + fc_b[0] - cA * mu * SW;

  float l[4];
  float ls = 0.f;
  #pragma unroll
  for (int i = 0; i < 4; ++i) {
    int n = t + i * 1024;
    l[i] = cA * Wv[n] + off;
    ls += l[i];
  }
  float LS = block_sum(ls, rbuf, bc, 16);
  float lmu = LS / 4096.0f;
  float lq = 0.f;
  #pragma unroll
  for (int i = 0; i < 4; ++i) { float d = l[i] - lmu; lq += d * d; }
  float LQ = block_sum(lq, rbuf, bc, 16);
  float lvar = LQ / 4096.0f;
  float sc = lbn_g[0] * rsqrtf(lvar + KEPS);
  float lb = lbn_b[0];
  #pragma unroll
  for (int i = 0; i < 4; ++i) {
    int n = t + i * 1024;
    out[n] = (l[i] - lmu) * sc + lb;
  }
}

// ---------------------------------------------------------------------------
extern "C" void kernel_launch(void* const* d_in, const int* in_sizes, int n_in,
                              void* d_out, int out_size, void* d_ws, size_t ws_size,
                              hipStream_t stream) {
  const float* prob  = (const float*)d_in[0];
  const float* gal   = (const float*)d_in[1];
  const float* bn_g  = (const float*)d_in[2];
  const float* bn_b  = (const float*)d_in[3];
  const float* fc_w  = (const float*)d_in[4];
  const float* fc_b  = (const float*)d_in[5];
  const float* lbn_g = (const float*)d_in[6];
  const float* lbn_b = (const float*)d_in[7];
  float* out = (float*)d_out;

  char* ws = (char*)d_ws;
  char* probF = ws;                                  // 3,145,728 B
  char* galF  = ws + 3145728;                        // 3,145,728 B
  float* Wv    = (float*)(ws + 6291456);             // 16384 B
  float* sPart = (float*)(ws + 6307840);             // 8192 B
  float* qPart = (float*)(ws + 6316032);             // 8192 B

  prep_kernel<<<512, 256, 0, stream>>>(prob, gal, probF, galF);
  pair_kernel<<<2048, 256, 0, stream>>>(galF, probF, fc_w, Wv, sPart, qPart);
  finalize_kernel<<<1, 1024, 0, stream>>>(Wv, sPart, qPart, fc_w, fc_b,
                                          bn_g, bn_b, lbn_g, lbn_b, out);
}

// Round 18
// 57.583 us; speedup vs baseline: 6.3403x; 6.3403x over previous
//
#include <hip/hip_runtime.h>
#include <hip/hip_bf16.h>
#include <stdint.h>

#define HW 192
#define NC 128
#define KEPS 1e-5f
#define SLICE_B 49152   /* bytes per image in frag layout */

typedef __attribute__((ext_vector_type(8))) short short8;
typedef __attribute__((ext_vector_type(4))) float f32x4;

__device__ __forceinline__ float max3f(float a, float b, float c) {
  float d;
  asm("v_max3_f32 %0, %1, %2, %3" : "=v"(d) : "v"(a), "v"(b), "v"(c));
  return d;
}

// ---------------------------------------------------------------------------
// Prep: f32 [n][C][HW] -> MFMA-fragment layout:
//   16B chunk (tile 0..11, ks 0..3, lane 0..63) at ((tile*4+ks)*64+lane)*16
//   holding img[c = ks*32 + (lane>>4)*8 + j][s = tile*16 + (lane&15)], j=0..7.
// ---------------------------------------------------------------------------
__global__ __launch_bounds__(256)
void prep_kernel(const float* __restrict__ prob,
                 const float* __restrict__ gal,
                 char* __restrict__ probF,
                 char* __restrict__ galF) {
  __shared__ unsigned short lds[32 * 194];
  const int b = blockIdx.x;
  const int slice = b >> 2;
  const int ks = b & 3;
  const bool isProbe = (slice < 64);
  const float* src = isProbe ? prob + (size_t)slice * NC * HW
                             : gal + (size_t)(slice - 64) * NC * HW;
  char* dstBase = isProbe ? probF + (size_t)slice * SLICE_B
                          : galF + (size_t)(slice - 64) * SLICE_B;
  const float* s0 = src + (size_t)(ks * 32) * HW;
  #pragma unroll
  for (int k = 0; k < 24; ++k) {
    int i = k * 256 + threadIdx.x;
    int cp = i / HW;
    int hw = i - cp * HW;
    lds[cp * 194 + hw] =
        __builtin_bit_cast(unsigned short, __float2bfloat16(s0[i]));
  }
  __syncthreads();
  #pragma unroll
  for (int rep = 0; rep < 3; ++rep) {
    int idx = rep * 256 + threadIdx.x;   // 0..767
    int tile = idx >> 6;
    int lane = idx & 63;
    int q = lane >> 4;
    int s = tile * 16 + (lane & 15);
    short8 pack;
    #pragma unroll
    for (int j = 0; j < 8; ++j)
      pack[j] = (short)lds[(q * 8 + j) * 194 + s];
    *(short8*)(dstBase + (((tile * 4 + ks) * 64 + lane) * 16)) = pack;
  }
}

template <int CTRL>
__device__ __forceinline__ float dpp_max(float x) {
  int xi = __builtin_bit_cast(int, x);
  int yi = __builtin_amdgcn_update_dpp(xi, xi, CTRL, 0xf, 0xf, false);
  return fmaxf(x, __builtin_bit_cast(float, yi));
}
__device__ __forceinline__ float ror16_max(float x) {
  x = dpp_max<0x121>(x);
  x = dpp_max<0x122>(x);
  x = dpp_max<0x124>(x);
  x = dpp_max<0x128>(x);
  return x;
}

// ---------------------------------------------------------------------------
// Pair kernel: barrier-free streaming + explicit software pipeline (R12,
// verified best: 49.2us pair). 2048 blocks = g*32 + pc (2 probes each);
// XCD = bid%8 = pc%8. 4 waves = 4 gallery row-groups of 48 (A persistent).
// Per probe: 12 column-groups of 16 cols; acc ping-pong (even/odd) breaks
// reduce<->MFMA WAR chains; B quads rotate through 3 buffers, loaded
// 2 groups ahead. No LDS staging; no main-loop barriers.
// NOTE: (256,2) is load-bearing — (256,3) miscompiles (R17, absmax 7.25),
// (256,4) spills catastrophically (R16, 368us). Do not raise.
// ---------------------------------------------------------------------------
__global__ __launch_bounds__(256, 2)
void pair_kernel(const char* __restrict__ galF,
                 const char* __restrict__ probF,
                 const float* __restrict__ fc_w,
                 float* __restrict__ Wout,
                 float* __restrict__ sPart,
                 float* __restrict__ qPart) {
  __shared__ float cmP[2][4][192];   // [probe][wid][col] col-max partials
  __shared__ float rmF[2][192];      // [probe][row] final row-max
  __shared__ float red[2][4];        // [probe][wid] W partials
  __shared__ float red2[8];

  const int tid = threadIdx.x;
  const int lane = tid & 63;
  const int wid = tid >> 6;          // gallery row group: rows wid*48..+47
  const int q = lane >> 4;
  const int r16 = lane & 15;

  const int g = blockIdx.x >> 5;
  const int pc = blockIdx.x & 31;    // probes 2pc, 2pc+1

  // persistent gallery A-frags (coalesced frag loads)
  const char* gB = galF + (size_t)g * SLICE_B + lane * 16;
  short8 a[3][4];
  #pragma unroll
  for (int m = 0; m < 3; ++m)
    #pragma unroll
    for (int ks = 0; ks < 4; ++ks)
      a[m][ks] = *(const short8*)(gB + (((wid * 3 + m) * 4 + ks) * 1024));

  const float w0 = fc_w[tid];                           // feat j = tid
  const float w1 = (tid < 128) ? fc_w[256 + tid] : 0.f; // feat j = 256+tid

  float s_acc = 0.f, q_acc = 0.f;
  const f32x4 zz = (f32x4){0.f, 0.f, 0.f, 0.f};

  #pragma unroll 1
  for (int pi = 0; pi < 2; ++pi) {
    const char* pB = probF + (size_t)(pc * 2 + pi) * SLICE_B + lane * 16;
    float rm[3][4];
    #pragma unroll
    for (int m = 0; m < 3; ++m)
      #pragma unroll
      for (int j = 0; j < 4; ++j) rm[m][j] = -1e30f;

    short8 b00, b01, b02, b03;   // buffer 0
    short8 b10, b11, b12, b13;   // buffer 1
    short8 b20, b21, b22, b23;   // buffer 2
    f32x4 aA0, aA1, aA2;         // acc even
    f32x4 aB0, aB1, aB2;         // acc odd

#define LOADQ(Q0, Q1, Q2, Q3, GRP) do {                         \
    const char* bb_ = pB + (GRP) * 4096;                        \
    Q0 = *(const short8*)(bb_);                                 \
    Q1 = *(const short8*)(bb_ + 1024);                          \
    Q2 = *(const short8*)(bb_ + 2048);                          \
    Q3 = *(const short8*)(bb_ + 3072);                          \
  } while (0)

#define MFMA_G(A0, A1, A2, Q0, Q1, Q2, Q3) do {                              \
    A0 = __builtin_amdgcn_mfma_f32_16x16x32_bf16(a[0][0], Q0, zz, 0, 0, 0);  \
    A1 = __builtin_amdgcn_mfma_f32_16x16x32_bf16(a[1][0], Q0, zz, 0, 0, 0);  \
    A2 = __builtin_amdgcn_mfma_f32_16x16x32_bf16(a[2][0], Q0, zz, 0, 0, 0);  \
    A0 = __builtin_amdgcn_mfma_f32_16x16x32_bf16(a[0][1], Q1, A0, 0, 0, 0);  \
    A1 = __builtin_amdgcn_mfma_f32_16x16x32_bf16(a[1][1], Q1, A1, 0, 0, 0);  \
    A2 = __builtin_amdgcn_mfma_f32_16x16x32_bf16(a[2][1], Q1, A2, 0, 0, 0);  \
    A0 = __builtin_amdgcn_mfma_f32_16x16x32_bf16(a[0][2], Q2, A0, 0, 0, 0);  \
    A1 = __builtin_amdgcn_mfma_f32_16x16x32_bf16(a[1][2], Q2, A1, 0, 0, 0);  \
    A2 = __builtin_amdgcn_mfma_f32_16x16x32_bf16(a[2][2], Q2, A2, 0, 0, 0);  \
    A0 = __builtin_amdgcn_mfma_f32_16x16x32_bf16(a[0][3], Q3, A0, 0, 0, 0);  \
    A1 = __builtin_amdgcn_mfma_f32_16x16x32_bf16(a[1][3], Q3, A1, 0, 0, 0);  \
    A2 = __builtin_amdgcn_mfma_f32_16x16x32_bf16(a[2][3], Q3, A2, 0, 0, 0);  \
  } while (0)

#define REDUCE_G(A0, A1, A2, GRP) do {                                       \
    float m0_ = max3f(A0[0], A0[1], A0[2]);                                  \
    float m1_ = max3f(A0[3], A1[0], A1[1]);                                  \
    float m2_ = max3f(A1[2], A1[3], A2[0]);                                  \
    float m3_ = max3f(A2[1], A2[2], A2[3]);                                  \
    float cm_ = fmaxf(max3f(m0_, m1_, m2_), m3_);                            \
    cm_ = fmaxf(cm_, __shfl_xor(cm_, 16));                                   \
    cm_ = fmaxf(cm_, __shfl_xor(cm_, 32));                                   \
    if (lane < 16) cmP[pi][wid][(GRP) * 16 + r16] = cm_;                     \
    rm[0][0] = fmaxf(rm[0][0], A0[0]); rm[0][1] = fmaxf(rm[0][1], A0[1]);    \
    rm[0][2] = fmaxf(rm[0][2], A0[2]); rm[0][3] = fmaxf(rm[0][3], A0[3]);    \
    rm[1][0] = fmaxf(rm[1][0], A1[0]); rm[1][1] = fmaxf(rm[1][1], A1[1]);    \
    rm[1][2] = fmaxf(rm[1][2], A1[2]); rm[1][3] = fmaxf(rm[1][3], A1[3]);    \
    rm[2][0] = fmaxf(rm[2][0], A2[0]); rm[2][1] = fmaxf(rm[2][1], A2[1]);    \
    rm[2][2] = fmaxf(rm[2][2], A2[2]); rm[2][3] = fmaxf(rm[2][3], A2[3]);    \
  } while (0)

    // prologue: 2 groups in flight
    LOADQ(b00, b01, b02, b03, 0);
    LOADQ(b10, b11, b12, b13, 1);

    __builtin_amdgcn_s_setprio(1);
    // g0
    LOADQ(b20, b21, b22, b23, 2);
    MFMA_G(aA0, aA1, aA2, b00, b01, b02, b03);
    // g1
    LOADQ(b00, b01, b02, b03, 3);
    MFMA_G(aB0, aB1, aB2, b10, b11, b12, b13);
    REDUCE_G(aA0, aA1, aA2, 0);
    // g2
    LOADQ(b10, b11, b12, b13, 4);
    MFMA_G(aA0, aA1, aA2, b20, b21, b22, b23);
    REDUCE_G(aB0, aB1, aB2, 1);
    // g3
    LOADQ(b20, b21, b22, b23, 5);
    MFMA_G(aB0, aB1, aB2, b00, b01, b02, b03);
    REDUCE_G(aA0, aA1, aA2, 2);
    // g4
    LOADQ(b00, b01, b02, b03, 6);
    MFMA_G(aA0, aA1, aA2, b10, b11, b12, b13);
    REDUCE_G(aB0, aB1, aB2, 3);
    // g5
    LOADQ(b10, b11, b12, b13, 7);
    MFMA_G(aB0, aB1, aB2, b20, b21, b22, b23);
    REDUCE_G(aA0, aA1, aA2, 4);
    // g6
    LOADQ(b20, b21, b22, b23, 8);
    MFMA_G(aA0, aA1, aA2, b00, b01, b02, b03);
    REDUCE_G(aB0, aB1, aB2, 5);
    // g7
    LOADQ(b00, b01, b02, b03, 9);
    MFMA_G(aB0, aB1, aB2, b10, b11, b12, b13);
    REDUCE_G(aA0, aA1, aA2, 6);
    // g8
    LOADQ(b10, b11, b12, b13, 10);
    MFMA_G(aA0, aA1, aA2, b20, b21, b22, b23);
    REDUCE_G(aB0, aB1, aB2, 7);
    // g9
    LOADQ(b20, b21, b22, b23, 11);
    MFMA_G(aB0, aB1, aB2, b00, b01, b02, b03);
    REDUCE_G(aA0, aA1, aA2, 8);
    // g10
    MFMA_G(aA0, aA1, aA2, b10, b11, b12, b13);
    REDUCE_G(aB0, aB1, aB2, 9);
    // g11
    MFMA_G(aB0, aB1, aB2, b20, b21, b22, b23);
    REDUCE_G(aA0, aA1, aA2, 10);
    // epilogue
    REDUCE_G(aB0, aB1, aB2, 11);
    __builtin_amdgcn_s_setprio(0);

#undef LOADQ
#undef MFMA_G
#undef REDUCE_G

    // finish row-max: 16-lane DPP fold, publish rows wid*48 + m*16 + q*4 + j
    #pragma unroll
    for (int m = 0; m < 3; ++m)
      #pragma unroll
      for (int j = 0; j < 4; ++j) {
        float v = ror16_max(rm[m][j]);
        if (r16 == j) rmF[pi][wid * 48 + m * 16 + q * 4 + j] = v;
      }
  }

  __syncthreads();   // all partials visible

  // ---- combine: both probes ----
  #pragma unroll
  for (int pi = 0; pi < 2; ++pi) {
    float v;
    if (tid < 192) {
      float c01 = fmaxf(cmP[pi][0][tid], cmP[pi][1][tid]);
      v = max3f(c01, cmP[pi][2][tid], cmP[pi][3][tid]);
    } else {
      v = rmF[pi][tid - 192];          // rows 0..63 -> feat j = tid
    }
    s_acc += v; q_acc += v * v;
    float w = v * w0;
    if (tid < 128) {
      float v1 = rmF[pi][tid + 64];    // rows 64..191 -> feat j = 256+tid
      s_acc += v1; q_acc += v1 * v1;
      w += v1 * w1;
    }
    #pragma unroll
    for (int msk = 1; msk < 64; msk <<= 1) w += __shfl_xor(w, msk);
    if (lane == 0) red[pi][wid] = w;
  }
  #pragma unroll
  for (int msk = 1; msk < 64; msk <<= 1) {
    s_acc += __shfl_xor(s_acc, msk);
    q_acc += __shfl_xor(q_acc, msk);
  }
  if (lane == 0) { red2[wid] = s_acc; red2[4 + wid] = q_acc; }
  __syncthreads();
  if (tid < 2)
    Wout[(pc * 2 + tid) * 64 + g] =
        red[tid][0] + red[tid][1] + red[tid][2] + red[tid][3];
  if (tid == 0) {
    sPart[blockIdx.x] = red2[0] + red2[1] + red2[2] + red2[3];
    qPart[blockIdx.x] = red2[4] + red2[5] + red2[6] + red2[7];
  }
}

// ---------------------------------------------------------------------------
// Finalize: exact BN -> fc -> BN chain. One block, 1024 threads.
// sPart/qPart have 2048 entries.
// ---------------------------------------------------------------------------
__device__ __forceinline__ float block_sum(float v, float* rbuf, float* bc, int nw) {
  int t = threadIdx.x, lane = t & 63, wid = t >> 6;
  #pragma unroll
  for (int m = 1; m < 64; m <<= 1) v += __shfl_xor(v, m);
  if (lane == 0) rbuf[wid] = v;
  __syncthreads();
  if (t == 0) {
    float r = 0.f;
    for (int i = 0; i < nw; ++i) r += rbuf[i];
    bc[0] = r;
  }
  __syncthreads();
  float res = bc[0];
  __syncthreads();
  return res;
}

__global__ __launch_bounds__(1024)
void finalize_kernel(const float* __restrict__ Wv,
                     const float* __restrict__ sPart,
                     const float* __restrict__ qPart,
                     const float* __restrict__ fc_w,
                     const float* __restrict__ fc_b,
                     const float* __restrict__ bn_g,
                     const float* __restrict__ bn_b,
                     const float* __restrict__ lbn_g,
                     const float* __restrict__ lbn_b,
                     float* __restrict__ out) {
  __shared__ float rbuf[16];
  __shared__ float bc[1];
  const int t = threadIdx.x;

  float S = block_sum(sPart[t] + sPart[t + 1024], rbuf, bc, 16);
  float Q = block_sum(qPart[t] + qPart[t + 1024], rbuf, bc, 16);
  float SW = block_sum((t < 384) ? fc_w[t] : 0.f, rbuf, bc, 16);

  const float Nf = 4096.0f * 384.0f;
  float mu = S / Nf;
  float var = Q / Nf - mu * mu;
  float istd = rsqrtf(var + KEPS);
  float cA = istd * bn_g[0];
  float off = bn_b[0] * SW + fc_b[0] - cA * mu * SW;

  float l[4];
  float ls = 0.f;
  #pragma unroll
  for (int i = 0; i < 4; ++i) {
    int n = t + i * 1024;
    l[i] = cA * Wv[n] + off;
    ls += l[i];
  }
  float LS = block_sum(ls, rbuf, bc, 16);
  float lmu = LS / 4096.0f;
  float lq = 0.f;
  #pragma unroll
  for (int i = 0; i < 4; ++i) { float d = l[i] - lmu; lq += d * d; }
  float LQ = block_sum(lq, rbuf, bc, 16);
  float lvar = LQ / 4096.0f;
  float sc = lbn_g[0] * rsqrtf(lvar + KEPS);
  float lb = lbn_b[0];
  #pragma unroll
  for (int i = 0; i < 4; ++i) {
    int n = t + i * 1024;
    out[n] = (l[i] - lmu) * sc + lb;
  }
}

// ---------------------------------------------------------------------------
extern "C" void kernel_launch(void* const* d_in, const int* in_sizes, int n_in,
                              void* d_out, int out_size, void* d_ws, size_t ws_size,
                              hipStream_t stream) {
  const float* prob  = (const float*)d_in[0];
  const float* gal   = (const float*)d_in[1];
  const float* bn_g  = (const float*)d_in[2];
  const float* bn_b  = (const float*)d_in[3];
  const float* fc_w  = (const float*)d_in[4];
  const float* fc_b  = (const float*)d_in[5];
  const float* lbn_g = (const float*)d_in[6];
  const float* lbn_b = (const float*)d_in[7];
  float* out = (float*)d_out;

  char* ws = (char*)d_ws;
  char* probF = ws;                                  // 3,145,728 B
  char* galF  = ws + 3145728;                        // 3,145,728 B
  float* Wv    = (float*)(ws + 6291456);             // 16384 B
  float* sPart = (float*)(ws + 6307840);             // 8192 B
  float* qPart = (float*)(ws + 6316032);             // 8192 B

  prep_kernel<<<512, 256, 0, stream>>>(prob, gal, probF, galF);
  pair_kernel<<<2048, 256, 0, stream>>>(galF, probF, fc_w, Wv, sPart, qPart);
  finalize_kernel<<<1, 1024, 0, stream>>>(Wv, sPart, qPart, fc_w, fc_b,
                                          bn_g, bn_b, lbn_g, lbn_b, out);
}